// Round 4
// baseline (177.015 us; speedup 1.0000x reference)
//
#include <hip/hip_runtime.h>

#define NPTS 512
#define BLOCK 256
#define XPS 68   // xp row stride (dwords): mult of 4 (16B rows), mod 32 = 4 staggers banks

#define GLOBAL_AS(p) ((const __attribute__((address_space(1))) void*)(p))
#define LDS_AS(p)    ((__attribute__((address_space(3))) void*)(p))

// ---------------------------------------------------------------------------
// R12: FUSED moments + solve. One block = one batch.
//
// Budget audit (R11 post-mortem): total 135.4 = harness poison fills (~85-90,
// fixed, 2x 256MiB @ ~41us inside the timed region) + moments ~40 + solve
// ~5-8. Fusing deletes the solve launch + the ws round-trip, and pushes the
// fused kernel's dur (~42-46us) past the fills into rocprof's top-5 so we
// finally see its FETCH/WRITE sizes.
//
// Read-cap ledger (moments phase, ALL land 2.76-2.95 TB/s logical read):
//   R3-R8 five VGPR structures + global_load_lds; R9 NT -> null; R10 2x
//   window, 0 barriers -> regressed (de-coalesced). Open theory: the 256MiB
//   poison dirties L3 every iteration; our read misses evict DIRTY lines ->
//   ~117MB writeback under the read stream -> combined ~5.8 TB/s = true
//   roofline. Discriminator = fused row's WRITE_SIZE (~1e8 => confirmed;
//   ~0 with hbm_gbps ~2.9 => genuine read-path cap).
//
// Fused solve: after the block reduction, thread 0 runs the R11 statically-
// indexed, branch-free f64 solve (Jacobi eig of H^T H, compare-exchange
// eigen-sort, Gram-Schmidt U, R = V U^T, det +1 by construction). The ~2us
// serial f64 chain hides under other resident blocks' staging waits
// (pipes <15% busy). Risk: R6's "per-wave fusion inflates 64x" — that was a
// different structure (solve in every wave); here it's 1 thread per block.
// ---------------------------------------------------------------------------
__global__ __launch_bounds__(BLOCK) void wproc_fused(
    const float* __restrict__ src,
    const float* __restrict__ tgt,
    const float* __restrict__ wts,
    float* __restrict__ out,
    int B)
{
    const int b = blockIdx.x;
    const int t = threadIdx.x;
    const int wave = t >> 6, lane = t & 63;

    // phase 1: 14336 B staging buffer; phase 2: xp[4][16][68] = 17408 B
    __shared__ __align__(16) char smem[4 * 16 * XPS * 4];
    __shared__ float red[4][16];

    const char* sb = (const char*)(src + (size_t)b * (NPTS * 3));
    const char* tb = (const char*)(tgt + (size_t)b * (NPTS * 3));
    const char* wb = (const char*)(wts + (size_t)b * NPTS);

    // ---- direct-to-LDS staging: 14 x 1KB chunks round-robined over waves ----
    for (int c = wave; c < 14; c += 4) {
        const char* g;
        if (c < 6)       g = sb + (size_t)c * 1024;
        else if (c < 12) g = tb + (size_t)(c - 6) * 1024;
        else             g = wb + (size_t)(c - 12) * 1024;
        __builtin_amdgcn_global_load_lds(
            GLOBAL_AS(g + lane * 16),
            LDS_AS(smem + c * 1024),
            16, 0, 2);
    }
    __syncthreads();   // compiler drains vmcnt before the barrier

    const float* s_s = (const float*)smem;            // [0, 6144)
    const float* s_t = (const float*)(smem + 6144);   // [6144, 12288)
    const float* s_w = (const float*)(smem + 12288);  // [12288, 14336)

    // ---- accumulate 16 moments over 2 points ----
    // [W, m_s(3), m_t(3), M(9) row-major M_ij = sum w*src_i*tgt_j]
    float acc[16];
    #pragma unroll
    for (int i = 0; i < 16; ++i) acc[i] = 0.f;

    #pragma unroll
    for (int k = 0; k < 2; ++k) {
        const int p = t + k * 256;
        float w = s_w[p];
        w = (w < 0.f) ? 0.f : w;  // WEIGHT_THRESHOLD = 0.0
        const float sx = s_s[3 * p + 0], sy = s_s[3 * p + 1], sz = s_s[3 * p + 2];
        const float tx = s_t[3 * p + 0], ty = s_t[3 * p + 1], tz = s_t[3 * p + 2];
        acc[0] += w;
        acc[1] += w * sx; acc[2] += w * sy; acc[3] += w * sz;
        acc[4] += w * tx; acc[5] += w * ty; acc[6] += w * tz;
        const float wsx = w * sx, wsy = w * sy, wsz = w * sz;
        acc[7]  += wsx * tx; acc[8]  += wsx * ty; acc[9]  += wsx * tz;
        acc[10] += wsy * tx; acc[11] += wsy * ty; acc[12] += wsy * tz;
        acc[13] += wsz * tx; acc[14] += wsz * ty; acc[15] += wsz * tz;
    }
    __syncthreads();   // all point reads done before xp overlays the buffer

    float (*xp)[16][XPS] = (float (*)[16][XPS])smem;
    #pragma unroll
    for (int m = 0; m < 16; ++m) xp[wave][m][lane] = acc[m];

    // wave-private: lane m+16q sums quarter q of row m (in-order DS, no barrier)
    {
        const int m = lane & 15, q = lane >> 4;
        const float4* row = (const float4*)&xp[wave][m][0] + 4 * q;
        float4 a0 = row[0], a1 = row[1], a2 = row[2], a3 = row[3];
        a0.x += a1.x; a0.y += a1.y; a0.z += a1.z; a0.w += a1.w;
        a2.x += a3.x; a2.y += a3.y; a2.z += a3.z; a2.w += a3.w;
        a0.x += a2.x; a0.y += a2.y; a0.z += a2.z; a0.w += a2.w;
        float v = (a0.x + a0.y) + (a0.z + a0.w);
        v += __shfl_xor(v, 16, 64);
        v += __shfl_xor(v, 32, 64);
        if (q == 0) red[wave][m] = v;
    }
    __syncthreads();

    if (t != 0) return;

    // ================= inline solve (thread 0 only), R11 math ==============
    double m[16];
    #pragma unroll
    for (int i = 0; i < 16; ++i)
        m[i] = (double)((red[0][i] + red[1][i]) + (red[2][i] + red[3][i]));

    const double T = m[0] + 1e-5;       // sum(w) + EPS
    const double f = 2.0 - m[0] / T;
    const double cs[3] = { m[1] / T, m[2] / T, m[3] / T };
    const double ct[3] = { m[4] / T, m[5] / T, m[6] / T };
    double H[3][3];
    #pragma unroll
    for (int i = 0; i < 3; ++i)
        #pragma unroll
        for (int j = 0; j < 3; ++j)
            H[i][j] = m[7 + i * 3 + j] / T - f * cs[i] * ct[j];

    // A = H^T H (symmetric PSD)
    double A[3][3];
    #pragma unroll
    for (int i = 0; i < 3; ++i)
        #pragma unroll
        for (int j = 0; j < 3; ++j)
            A[i][j] = H[0][i] * H[0][j] + H[1][i] * H[1][j] + H[2][i] * H[2][j];

    // Jacobi eigendecomposition, fully unrolled, branch-free.
    double V[3][3] = { {1, 0, 0}, {0, 1, 0}, {0, 0, 1} };
    #pragma unroll
    for (int sweep = 0; sweep < 5; ++sweep) {
        #pragma unroll
        for (int pair = 0; pair < 3; ++pair) {
            const int p = (pair == 2) ? 1 : 0;
            const int q = (pair == 0) ? 1 : 2;
            const double apq = A[p][q];
            const double theta = (A[q][q] - A[p][p]) / (2.0 * apq);
            const double tt = ((theta >= 0.0) ? 1.0 : -1.0)
                            / (fabs(theta) + sqrt(theta * theta + 1.0));
            double c  = 1.0 / sqrt(tt * tt + 1.0);
            double sn = tt * c;
            const bool zero = (apq == 0.0);   // selects sanitize inf/NaN path
            c  = zero ? 1.0 : c;
            sn = zero ? 0.0 : sn;
            #pragma unroll
            for (int k = 0; k < 3; ++k) {  // A <- A G
                const double akp = A[k][p], akq = A[k][q];
                A[k][p] = c * akp - sn * akq;
                A[k][q] = sn * akp + c * akq;
            }
            #pragma unroll
            for (int k = 0; k < 3; ++k) {  // A <- G^T A
                const double apk = A[p][k], aqk = A[q][k];
                A[p][k] = c * apk - sn * aqk;
                A[q][k] = sn * apk + c * aqk;
            }
            #pragma unroll
            for (int k = 0; k < 3; ++k) {  // V <- V G
                const double vkp = V[k][p], vkq = V[k][q];
                V[k][p] = c * vkp - sn * vkq;
                V[k][q] = sn * vkp + c * vkq;
            }
        }
    }

    // eigen-sort descending via static compare-exchange network
    double lam[3] = { A[0][0], A[1][1], A[2][2] };
    #define CSWAP(a_, b_) do {                                                \
        const bool sw_ = lam[a_] < lam[b_];                                   \
        const double tl_ = lam[a_];                                           \
        lam[a_] = sw_ ? lam[b_] : lam[a_];                                    \
        lam[b_] = sw_ ? tl_ : lam[b_];                                        \
        _Pragma("unroll")                                                     \
        for (int k = 0; k < 3; ++k) {                                         \
            const double tv_ = V[k][a_];                                      \
            V[k][a_] = sw_ ? V[k][b_] : V[k][a_];                             \
            V[k][b_] = sw_ ? tv_ : V[k][b_];                                  \
        }                                                                     \
    } while (0)
    CSWAP(0, 1); CSWAP(0, 2); CSWAP(1, 2);
    #undef CSWAP

    const double v1[3] = { V[0][0], V[1][0], V[2][0] };
    const double v2[3] = { V[0][1], V[1][1], V[2][1] };
    const double v3[3] = { v1[1] * v2[2] - v1[2] * v2[1],
                           v1[2] * v2[0] - v1[0] * v2[2],
                           v1[0] * v2[1] - v1[1] * v2[0] };

    double u1[3], u2[3], u3[3];
    #pragma unroll
    for (int i = 0; i < 3; ++i)
        u1[i] = H[i][0] * v1[0] + H[i][1] * v1[1] + H[i][2] * v1[2];
    double n1 = sqrt(u1[0] * u1[0] + u1[1] * u1[1] + u1[2] * u1[2]);
    n1 = (n1 > 1e-30) ? n1 : 1e-30;
    #pragma unroll
    for (int i = 0; i < 3; ++i) u1[i] /= n1;

    #pragma unroll
    for (int i = 0; i < 3; ++i)
        u2[i] = H[i][0] * v2[0] + H[i][1] * v2[1] + H[i][2] * v2[2];
    const double d12 = u1[0] * u2[0] + u1[1] * u2[1] + u1[2] * u2[2];
    #pragma unroll
    for (int i = 0; i < 3; ++i) u2[i] -= d12 * u1[i];
    double n2 = sqrt(u2[0] * u2[0] + u2[1] * u2[1] + u2[2] * u2[2]);
    n2 = (n2 > 1e-30) ? n2 : 1e-30;
    #pragma unroll
    for (int i = 0; i < 3; ++i) u2[i] /= n2;

    u3[0] = u1[1] * u2[2] - u1[2] * u2[1];
    u3[1] = u1[2] * u2[0] - u1[0] * u2[2];
    u3[2] = u1[0] * u2[1] - u1[1] * u2[0];

    double R[3][3];
    #pragma unroll
    for (int i = 0; i < 3; ++i)
        #pragma unroll
        for (int j = 0; j < 3; ++j)
            R[i][j] = v1[i] * u1[j] + v2[i] * u2[j] + v3[i] * u3[j];

    double tv[3];
    #pragma unroll
    for (int i = 0; i < 3; ++i)
        tv[i] = ct[i] - (R[i][0] * cs[0] + R[i][1] * cs[1] + R[i][2] * cs[2]);

    float* outR = out + (size_t)b * 9;
    #pragma unroll
    for (int i = 0; i < 3; ++i)
        #pragma unroll
        for (int j = 0; j < 3; ++j)
            outR[i * 3 + j] = (float)R[i][j];
    float* outT = out + (size_t)B * 9 + (size_t)b * 3;
    #pragma unroll
    for (int i = 0; i < 3; ++i) outT[i] = (float)tv[i];
}

extern "C" void kernel_launch(void* const* d_in, const int* in_sizes, int n_in,
                              void* d_out, int out_size, void* d_ws, size_t ws_size,
                              hipStream_t stream) {
    const float* src = (const float*)d_in[0];
    const float* tgt = (const float*)d_in[1];
    const float* wts = (const float*)d_in[2];
    float* out = (float*)d_out;
    const int B = out_size / 12;  // 9 (R) + 3 (t) floats per batch; B=8192

    wproc_fused<<<B, BLOCK, 0, stream>>>(src, tgt, wts, out, B);
}

// Round 7
// 139.627 us; speedup vs baseline: 1.2678x; 1.2678x over previous
//
#include <hip/hip_runtime.h>

#define NPTS 512
#define BLOCK 256
#define BLOCK_S 64
#define XPS 68      // xp row stride (dwords): mult of 4 (16B rows), bank stagger
#define GRID_M 768  // 3 blocks/CU x 256 CUs, all co-resident (LDS 46.6 KB/block)

#define GLOBAL_AS(p) ((const __attribute__((address_space(1))) void*)(p))
#define LDS_AS(p)    ((__attribute__((address_space(3))) void*)(p))

// ---------------------------------------------------------------------------
// Kernel 1: weighted moments — R15: persistent + issue-early prefetch built
// ONLY from proven primitives (__syncthreads; no inline asm, no raw barriers).
//
// Ledger: R3-R9 one-shot structures all ~2.9 TB/s logical read, pipes <15%
// busy (latency/structure-bound, not BW: R12 showed FETCH=57.5MB — L3 serves
// ~half — and staging-phase HBM ~800 GB/s). R13/R14: counted-vmcnt pipeline
// raced TWICE (absmax 1.6-2.0, mechanism never isolated from source) ->
// abandoned per m152 discipline.
//
// R15 keeps the two wins with safe sync:
//   - persistent blocks: grid=768 (3/CU), grid-stride over 8192 batches.
//   - issue-early: batch i+G's global_load_lds issued BEFORE batch i's
//     accumulate; the single __syncthreads at iter end drains it (vmcnt 0)
//     AFTER the DMA had the whole accumulate+reduce phase to fly.
//   - ONE barrier per batch, enabled by:
//       (a) DEDICATED xp[4][16][68] (transpose+quarter-sum is wave-private,
//           in-order DS -> no barrier between point reads and xp writes);
//       (b) red[2][4][16] double-buffered (wave-0's post-barrier combine of
//           iter i can't race other waves' iter-i+1 red writes).
// Correctness: buf[p^1] DMA issued at iter i; its last readers (iter i-1
// accumulate) were lgkm-drained by iter i-1's __syncthreads. buf[p] reads at
// iter i see batch-i data drained by iter i-1's barrier. All wave-private DS
// is program-ordered. Store of iter i rides across iter i+1 (harmless).
// ---------------------------------------------------------------------------
__global__ __launch_bounds__(BLOCK) void wproc_moments(
    const float* __restrict__ src,
    const float* __restrict__ tgt,
    const float* __restrict__ wts,
    float* __restrict__ ws,
    int B)
{
    const int t = threadIdx.x;
    const int wave = t >> 6, lane = t & 63;

    __shared__ __align__(16) char buf[2][14336];      // staging: src|tgt|w
    __shared__ __align__(16) float xp[4][16][XPS];    // dedicated transpose
    __shared__ float red[2][4][16];                   // double-buffered

    auto stage = [&](int b, char* dst) {
        const char* sb = (const char*)(src + (size_t)b * (NPTS * 3));
        const char* tb = (const char*)(tgt + (size_t)b * (NPTS * 3));
        const char* wb = (const char*)(wts + (size_t)b * NPTS);
        for (int c = wave; c < 14; c += 4) {   // waves 0,1: 4 chunks; 2,3: 3
            const char* g;
            if (c < 6)       g = sb + (size_t)c * 1024;
            else if (c < 12) g = tb + (size_t)(c - 6) * 1024;
            else             g = wb + (size_t)(c - 12) * 1024;
            __builtin_amdgcn_global_load_lds(
                GLOBAL_AS(g + lane * 16),
                LDS_AS(dst + c * 1024),
                16, 0, 2);
        }
    };

    int b = blockIdx.x;
    if (b < B) stage(b, buf[0]);
    __syncthreads();   // batch b landed

    int p = 0;
    for (; b < B; b += GRID_M, p ^= 1) {
        const int bn = b + GRID_M;
        if (bn < B) stage(bn, buf[p ^ 1]);   // issue-early prefetch

        const float* s_s = (const float*)(buf[p]);          // [0, 6144)
        const float* s_t = (const float*)(buf[p] + 6144);   // [6144, 12288)
        const float* s_w = (const float*)(buf[p] + 12288);  // [12288, 14336)

        // [W, m_s(3), m_t(3), M(9) row-major M_ij = sum w*src_i*tgt_j]
        float acc[16];
        #pragma unroll
        for (int j = 0; j < 16; ++j) acc[j] = 0.f;

        #pragma unroll
        for (int k = 0; k < 2; ++k) {
            const int pt = t + k * 256;
            float w = s_w[pt];
            w = (w < 0.f) ? 0.f : w;  // WEIGHT_THRESHOLD = 0.0
            const float sx = s_s[3 * pt + 0], sy = s_s[3 * pt + 1], sz = s_s[3 * pt + 2];
            const float tx = s_t[3 * pt + 0], ty = s_t[3 * pt + 1], tz = s_t[3 * pt + 2];
            acc[0] += w;
            acc[1] += w * sx; acc[2] += w * sy; acc[3] += w * sz;
            acc[4] += w * tx; acc[5] += w * ty; acc[6] += w * tz;
            const float wsx = w * sx, wsy = w * sy, wsz = w * sz;
            acc[7]  += wsx * tx; acc[8]  += wsx * ty; acc[9]  += wsx * tz;
            acc[10] += wsy * tx; acc[11] += wsy * ty; acc[12] += wsy * tz;
            acc[13] += wsz * tx; acc[14] += wsz * ty; acc[15] += wsz * tz;
        }

        // wave-private transpose + quarter-sum (own rows, in-order DS):
        // no barrier needed before or inside this section.
        #pragma unroll
        for (int mI = 0; mI < 16; ++mI) xp[wave][mI][lane] = acc[mI];
        {
            const int mI = lane & 15, q = lane >> 4;
            const float4* row = (const float4*)&xp[wave][mI][0] + 4 * q;
            float4 a0 = row[0], a1 = row[1], a2 = row[2], a3 = row[3];
            a0.x += a1.x; a0.y += a1.y; a0.z += a1.z; a0.w += a1.w;
            a2.x += a3.x; a2.y += a3.y; a2.z += a3.z; a2.w += a3.w;
            a0.x += a2.x; a0.y += a2.y; a0.z += a2.z; a0.w += a2.w;
            float v = (a0.x + a0.y) + (a0.z + a0.w);
            v += __shfl_xor(v, 16, 64);
            v += __shfl_xor(v, 32, 64);
            if (q == 0) red[p][wave][mI] = v;
        }

        __syncthreads();   // drains next batch's DMA + all LDS; red[p] visible

        if (t < 16) {
            ws[(size_t)b * 16 + t] =
                (red[p][0][t] + red[p][1][t]) + (red[p][2][t] + red[p][3][t]);
        }
    }
}

// ---------------------------------------------------------------------------
// Kernel 2: per-batch 3x3 Procrustes solve — R11 version (statically indexed,
// branch-free; proved -8us vs dynamic-index original). 64-thread blocks.
//
// Algebra: with T = sum(w)+eps:
//   H = M/T - (2 - W/T)(m_s/T)(m_t/T)^T; Jacobi eig of H^T H -> V;
//   v3 = v1 x v2; u_i = H v_i Gram-Schmidt; u3 = u1 x u2; R = V U^T
//   (det +1 by construction == reference's diag(1,1,sign(det)) fix).
// ---------------------------------------------------------------------------
__global__ __launch_bounds__(BLOCK_S) void wproc_solve(
    const float* __restrict__ ws,
    float* __restrict__ out,
    int B)
{
    const int b = blockIdx.x * BLOCK_S + threadIdx.x;
    if (b >= B) return;

    double m[16];
    #pragma unroll
    for (int i = 0; i < 16; ++i) m[i] = (double)ws[(size_t)b * 16 + i];

    const double T = m[0] + 1e-5;       // sum(w) + EPS
    const double f = 2.0 - m[0] / T;
    const double cs[3] = { m[1] / T, m[2] / T, m[3] / T };
    const double ct[3] = { m[4] / T, m[5] / T, m[6] / T };
    double H[3][3];
    #pragma unroll
    for (int i = 0; i < 3; ++i)
        #pragma unroll
        for (int j = 0; j < 3; ++j)
            H[i][j] = m[7 + i * 3 + j] / T - f * cs[i] * ct[j];

    double A[3][3];
    #pragma unroll
    for (int i = 0; i < 3; ++i)
        #pragma unroll
        for (int j = 0; j < 3; ++j)
            A[i][j] = H[0][i] * H[0][j] + H[1][i] * H[1][j] + H[2][i] * H[2][j];

    double V[3][3] = { {1, 0, 0}, {0, 1, 0}, {0, 0, 1} };
    #pragma unroll
    for (int sweep = 0; sweep < 5; ++sweep) {
        #pragma unroll
        for (int pair = 0; pair < 3; ++pair) {
            const int p = (pair == 2) ? 1 : 0;
            const int q = (pair == 0) ? 1 : 2;
            const double apq = A[p][q];
            const double theta = (A[q][q] - A[p][p]) / (2.0 * apq);
            const double tt = ((theta >= 0.0) ? 1.0 : -1.0)
                            / (fabs(theta) + sqrt(theta * theta + 1.0));
            double c  = 1.0 / sqrt(tt * tt + 1.0);
            double sn = tt * c;
            const bool zero = (apq == 0.0);   // selects sanitize inf/NaN path
            c  = zero ? 1.0 : c;
            sn = zero ? 0.0 : sn;
            #pragma unroll
            for (int k = 0; k < 3; ++k) {
                const double akp = A[k][p], akq = A[k][q];
                A[k][p] = c * akp - sn * akq;
                A[k][q] = sn * akp + c * akq;
            }
            #pragma unroll
            for (int k = 0; k < 3; ++k) {
                const double apk = A[p][k], aqk = A[q][k];
                A[p][k] = c * apk - sn * aqk;
                A[q][k] = sn * apk + c * aqk;
            }
            #pragma unroll
            for (int k = 0; k < 3; ++k) {
                const double vkp = V[k][p], vkq = V[k][q];
                V[k][p] = c * vkp - sn * vkq;
                V[k][q] = sn * vkp + c * vkq;
            }
        }
    }

    double lam[3] = { A[0][0], A[1][1], A[2][2] };
    #define CSWAP(a_, b_) do {                                                \
        const bool sw_ = lam[a_] < lam[b_];                                   \
        const double tl_ = lam[a_];                                           \
        lam[a_] = sw_ ? lam[b_] : lam[a_];                                    \
        lam[b_] = sw_ ? tl_ : lam[b_];                                        \
        _Pragma("unroll")                                                     \
        for (int k = 0; k < 3; ++k) {                                         \
            const double tv_ = V[k][a_];                                      \
            V[k][a_] = sw_ ? V[k][b_] : V[k][a_];                             \
            V[k][b_] = sw_ ? tv_ : V[k][b_];                                  \
        }                                                                     \
    } while (0)
    CSWAP(0, 1); CSWAP(0, 2); CSWAP(1, 2);
    #undef CSWAP

    const double v1[3] = { V[0][0], V[1][0], V[2][0] };
    const double v2[3] = { V[0][1], V[1][1], V[2][1] };
    const double v3[3] = { v1[1] * v2[2] - v1[2] * v2[1],
                           v1[2] * v2[0] - v1[0] * v2[2],
                           v1[0] * v2[1] - v1[1] * v2[0] };

    double u1[3], u2[3], u3[3];
    #pragma unroll
    for (int i = 0; i < 3; ++i)
        u1[i] = H[i][0] * v1[0] + H[i][1] * v1[1] + H[i][2] * v1[2];
    double n1 = sqrt(u1[0] * u1[0] + u1[1] * u1[1] + u1[2] * u1[2]);
    n1 = (n1 > 1e-30) ? n1 : 1e-30;
    #pragma unroll
    for (int i = 0; i < 3; ++i) u1[i] /= n1;

    #pragma unroll
    for (int i = 0; i < 3; ++i)
        u2[i] = H[i][0] * v2[0] + H[i][1] * v2[1] + H[i][2] * v2[2];
    const double d12 = u1[0] * u2[0] + u1[1] * u2[1] + u1[2] * u2[2];
    #pragma unroll
    for (int i = 0; i < 3; ++i) u2[i] -= d12 * u1[i];
    double n2 = sqrt(u2[0] * u2[0] + u2[1] * u2[1] + u2[2] * u2[2]);
    n2 = (n2 > 1e-30) ? n2 : 1e-30;
    #pragma unroll
    for (int i = 0; i < 3; ++i) u2[i] /= n2;

    u3[0] = u1[1] * u2[2] - u1[2] * u2[1];
    u3[1] = u1[2] * u2[0] - u1[0] * u2[2];
    u3[2] = u1[0] * u2[1] - u1[1] * u2[0];

    double R[3][3];
    #pragma unroll
    for (int i = 0; i < 3; ++i)
        #pragma unroll
        for (int j = 0; j < 3; ++j)
            R[i][j] = v1[i] * u1[j] + v2[i] * u2[j] + v3[i] * u3[j];

    double tv[3];
    #pragma unroll
    for (int i = 0; i < 3; ++i)
        tv[i] = ct[i] - (R[i][0] * cs[0] + R[i][1] * cs[1] + R[i][2] * cs[2]);

    float* outR = out + (size_t)b * 9;
    #pragma unroll
    for (int i = 0; i < 3; ++i)
        #pragma unroll
        for (int j = 0; j < 3; ++j)
            outR[i * 3 + j] = (float)R[i][j];
    float* outT = out + (size_t)B * 9 + (size_t)b * 3;
    #pragma unroll
    for (int i = 0; i < 3; ++i) outT[i] = (float)tv[i];
}

extern "C" void kernel_launch(void* const* d_in, const int* in_sizes, int n_in,
                              void* d_out, int out_size, void* d_ws, size_t ws_size,
                              hipStream_t stream) {
    const float* src = (const float*)d_in[0];
    const float* tgt = (const float*)d_in[1];
    const float* wts = (const float*)d_in[2];
    float* out = (float*)d_out;
    float* ws = (float*)d_ws;   // 16 floats per batch = 512 KB
    const int B = out_size / 12;  // 9 (R) + 3 (t) floats per batch; B=8192

    wproc_moments<<<GRID_M, BLOCK, 0, stream>>>(src, tgt, wts, ws, B);
    wproc_solve<<<(B + BLOCK_S - 1) / BLOCK_S, BLOCK_S, 0, stream>>>(ws, out, B);
}

// Round 8
// 133.916 us; speedup vs baseline: 1.3218x; 1.0426x over previous
//
#include <hip/hip_runtime.h>

#define NPTS 512
#define BLOCK 256
#define BLOCK_S 64
#define XPS 68   // xp row stride (dwords): mult of 4 (16B rows), mod 32 = 4 staggers banks

#define GLOBAL_AS(p) ((const __attribute__((address_space(1))) void*)(p))
#define LDS_AS(p)    ((__attribute__((address_space(3))) void*)(p))

// ---------------------------------------------------------------------------
// FINAL (R16 = exact revert to R11, best measured: 135.4 us).
//
// Read-path roofline ledger — ten moments structures, one invariant
// (~2.76-2.95 TB/s logical read):
//   R3-R8: five VGPR load structures + one-shot global_load_lds staging.
//   R9:    NT no-allocate policy -> null.
//   R10:   2x in-flight window, 0 barriers, wave/batch -> regressed.
//   R13/14: counted-vmcnt persistent pipeline -> raced twice, abandoned.
//   R15:   persistent blocks + issue-early prefetch + 1 barrier/batch ->
//          139.6 (DMA overlap gained NOTHING -> not latency-bound).
// External anchor: m13 "6.29 TB/s copy" = 3.15 TB/s PER DIRECTION; write-only
// fills do 6.5 TB/s. Conclusion: sustained read-return path ~3.1 TB/s;
// we run at ~93% of it with mandatory, irreducible traffic (117 MB read
// exactly once). Moments floor ~38-40 us. Solve ~5-6 us (R11 static-index
// rewrite, -8.1 us vs dynamic). R12 proved fusion regresses (serial f64
// tails serialize on-CU). Remainder of dur_us is harness poison fills +
// launch overhead, not controllable from kernel code.
// ---------------------------------------------------------------------------
__global__ __launch_bounds__(BLOCK) void wproc_moments(
    const float* __restrict__ src,
    const float* __restrict__ tgt,
    const float* __restrict__ wts,
    float* __restrict__ ws)
{
    const int b = blockIdx.x;
    const int t = threadIdx.x;
    const int wave = t >> 6, lane = t & 63;

    // phase 1: 14336 B staging buffer; phase 2: xp[4][16][68] = 17408 B
    __shared__ __align__(16) char smem[4 * 16 * XPS * 4];
    __shared__ float red[4][16];

    const char* sb = (const char*)(src + (size_t)b * (NPTS * 3));
    const char* tb = (const char*)(tgt + (size_t)b * (NPTS * 3));
    const char* wb = (const char*)(wts + (size_t)b * NPTS);

    // ---- direct-to-LDS staging: 14 x 1KB chunks round-robined over waves ----
    for (int c = wave; c < 14; c += 4) {
        const char* g;
        if (c < 6)       g = sb + (size_t)c * 1024;
        else if (c < 12) g = tb + (size_t)(c - 6) * 1024;
        else             g = wb + (size_t)(c - 12) * 1024;
        __builtin_amdgcn_global_load_lds(
            GLOBAL_AS(g + lane * 16),
            LDS_AS(smem + c * 1024),
            16, 0, 2);
    }
    __syncthreads();   // compiler drains vmcnt before the barrier

    const float* s_s = (const float*)smem;            // [0, 6144)
    const float* s_t = (const float*)(smem + 6144);   // [6144, 12288)
    const float* s_w = (const float*)(smem + 12288);  // [12288, 14336)

    // ---- accumulate 16 moments over 2 points ----
    // [W, m_s(3), m_t(3), M(9) row-major M_ij = sum w*src_i*tgt_j]
    float acc[16];
    #pragma unroll
    for (int i = 0; i < 16; ++i) acc[i] = 0.f;

    #pragma unroll
    for (int k = 0; k < 2; ++k) {
        const int p = t + k * 256;
        float w = s_w[p];
        w = (w < 0.f) ? 0.f : w;  // WEIGHT_THRESHOLD = 0.0
        const float sx = s_s[3 * p + 0], sy = s_s[3 * p + 1], sz = s_s[3 * p + 2];
        const float tx = s_t[3 * p + 0], ty = s_t[3 * p + 1], tz = s_t[3 * p + 2];
        acc[0] += w;
        acc[1] += w * sx; acc[2] += w * sy; acc[3] += w * sz;
        acc[4] += w * tx; acc[5] += w * ty; acc[6] += w * tz;
        const float wsx = w * sx, wsy = w * sy, wsz = w * sz;
        acc[7]  += wsx * tx; acc[8]  += wsx * ty; acc[9]  += wsx * tz;
        acc[10] += wsy * tx; acc[11] += wsy * ty; acc[12] += wsy * tz;
        acc[13] += wsz * tx; acc[14] += wsz * ty; acc[15] += wsz * tz;
    }
    __syncthreads();   // all point reads done before xp overlays the buffer

    float (*xp)[16][XPS] = (float (*)[16][XPS])smem;
    #pragma unroll
    for (int m = 0; m < 16; ++m) xp[wave][m][lane] = acc[m];

    // wave-private: lane m+16q sums quarter q of row m (in-order DS, no barrier)
    {
        const int m = lane & 15, q = lane >> 4;
        const float4* row = (const float4*)&xp[wave][m][0] + 4 * q;
        float4 a0 = row[0], a1 = row[1], a2 = row[2], a3 = row[3];
        a0.x += a1.x; a0.y += a1.y; a0.z += a1.z; a0.w += a1.w;
        a2.x += a3.x; a2.y += a3.y; a2.z += a3.z; a2.w += a3.w;
        a0.x += a2.x; a0.y += a2.y; a0.z += a2.z; a0.w += a2.w;
        float v = (a0.x + a0.y) + (a0.z + a0.w);
        v += __shfl_xor(v, 16, 64);
        v += __shfl_xor(v, 32, 64);
        if (q == 0) red[wave][m] = v;
    }
    __syncthreads();

    if (t < 16) {
        ws[(size_t)b * 16 + t] =
            (red[0][t] + red[1][t]) + (red[2][t] + red[3][t]);
    }
}

// ---------------------------------------------------------------------------
// Kernel 2: per-batch 3x3 Procrustes solve — R11 (statically indexed,
// branch-free; -8.1 us vs dynamic-index original). 64-thread blocks.
//
// Algebra: with T = sum(w)+eps:
//   H = M/T - (2 - W/T)(m_s/T)(m_t/T)^T; Jacobi eig of H^T H -> V;
//   v3 = v1 x v2; u_i = H v_i Gram-Schmidt; u3 = u1 x u2; R = V U^T
//   (det +1 by construction == reference's diag(1,1,sign(det)) fix).
// ---------------------------------------------------------------------------
__global__ __launch_bounds__(BLOCK_S) void wproc_solve(
    const float* __restrict__ ws,
    float* __restrict__ out,
    int B)
{
    const int b = blockIdx.x * BLOCK_S + threadIdx.x;
    if (b >= B) return;

    double m[16];
    #pragma unroll
    for (int i = 0; i < 16; ++i) m[i] = (double)ws[(size_t)b * 16 + i];

    const double T = m[0] + 1e-5;       // sum(w) + EPS
    const double f = 2.0 - m[0] / T;
    const double cs[3] = { m[1] / T, m[2] / T, m[3] / T };
    const double ct[3] = { m[4] / T, m[5] / T, m[6] / T };
    double H[3][3];
    #pragma unroll
    for (int i = 0; i < 3; ++i)
        #pragma unroll
        for (int j = 0; j < 3; ++j)
            H[i][j] = m[7 + i * 3 + j] / T - f * cs[i] * ct[j];

    double A[3][3];
    #pragma unroll
    for (int i = 0; i < 3; ++i)
        #pragma unroll
        for (int j = 0; j < 3; ++j)
            A[i][j] = H[0][i] * H[0][j] + H[1][i] * H[1][j] + H[2][i] * H[2][j];

    double V[3][3] = { {1, 0, 0}, {0, 1, 0}, {0, 0, 1} };
    #pragma unroll
    for (int sweep = 0; sweep < 5; ++sweep) {
        #pragma unroll
        for (int pair = 0; pair < 3; ++pair) {
            const int p = (pair == 2) ? 1 : 0;
            const int q = (pair == 0) ? 1 : 2;
            const double apq = A[p][q];
            const double theta = (A[q][q] - A[p][p]) / (2.0 * apq);
            const double tt = ((theta >= 0.0) ? 1.0 : -1.0)
                            / (fabs(theta) + sqrt(theta * theta + 1.0));
            double c  = 1.0 / sqrt(tt * tt + 1.0);
            double sn = tt * c;
            const bool zero = (apq == 0.0);   // selects sanitize inf/NaN path
            c  = zero ? 1.0 : c;
            sn = zero ? 0.0 : sn;
            #pragma unroll
            for (int k = 0; k < 3; ++k) {
                const double akp = A[k][p], akq = A[k][q];
                A[k][p] = c * akp - sn * akq;
                A[k][q] = sn * akp + c * akq;
            }
            #pragma unroll
            for (int k = 0; k < 3; ++k) {
                const double apk = A[p][k], aqk = A[q][k];
                A[p][k] = c * apk - sn * aqk;
                A[q][k] = sn * apk + c * aqk;
            }
            #pragma unroll
            for (int k = 0; k < 3; ++k) {
                const double vkp = V[k][p], vkq = V[k][q];
                V[k][p] = c * vkp - sn * vkq;
                V[k][q] = sn * vkp + c * vkq;
            }
        }
    }

    double lam[3] = { A[0][0], A[1][1], A[2][2] };
    #define CSWAP(a_, b_) do {                                                \
        const bool sw_ = lam[a_] < lam[b_];                                   \
        const double tl_ = lam[a_];                                           \
        lam[a_] = sw_ ? lam[b_] : lam[a_];                                    \
        lam[b_] = sw_ ? tl_ : lam[b_];                                        \
        _Pragma("unroll")                                                     \
        for (int k = 0; k < 3; ++k) {                                         \
            const double tv_ = V[k][a_];                                      \
            V[k][a_] = sw_ ? V[k][b_] : V[k][a_];                             \
            V[k][b_] = sw_ ? tv_ : V[k][b_];                                  \
        }                                                                     \
    } while (0)
    CSWAP(0, 1); CSWAP(0, 2); CSWAP(1, 2);
    #undef CSWAP

    const double v1[3] = { V[0][0], V[1][0], V[2][0] };
    const double v2[3] = { V[0][1], V[1][1], V[2][1] };
    const double v3[3] = { v1[1] * v2[2] - v1[2] * v2[1],
                           v1[2] * v2[0] - v1[0] * v2[2],
                           v1[0] * v2[1] - v1[1] * v2[0] };

    double u1[3], u2[3], u3[3];
    #pragma unroll
    for (int i = 0; i < 3; ++i)
        u1[i] = H[i][0] * v1[0] + H[i][1] * v1[1] + H[i][2] * v1[2];
    double n1 = sqrt(u1[0] * u1[0] + u1[1] * u1[1] + u1[2] * u1[2]);
    n1 = (n1 > 1e-30) ? n1 : 1e-30;
    #pragma unroll
    for (int i = 0; i < 3; ++i) u1[i] /= n1;

    #pragma unroll
    for (int i = 0; i < 3; ++i)
        u2[i] = H[i][0] * v2[0] + H[i][1] * v2[1] + H[i][2] * v2[2];
    const double d12 = u1[0] * u2[0] + u1[1] * u2[1] + u1[2] * u2[2];
    #pragma unroll
    for (int i = 0; i < 3; ++i) u2[i] -= d12 * u1[i];
    double n2 = sqrt(u2[0] * u2[0] + u2[1] * u2[1] + u2[2] * u2[2]);
    n2 = (n2 > 1e-30) ? n2 : 1e-30;
    #pragma unroll
    for (int i = 0; i < 3; ++i) u2[i] /= n2;

    u3[0] = u1[1] * u2[2] - u1[2] * u2[1];
    u3[1] = u1[2] * u2[0] - u1[0] * u2[2];
    u3[2] = u1[0] * u2[1] - u1[1] * u2[0];

    double R[3][3];
    #pragma unroll
    for (int i = 0; i < 3; ++i)
        #pragma unroll
        for (int j = 0; j < 3; ++j)
            R[i][j] = v1[i] * u1[j] + v2[i] * u2[j] + v3[i] * u3[j];

    double tv[3];
    #pragma unroll
    for (int i = 0; i < 3; ++i)
        tv[i] = ct[i] - (R[i][0] * cs[0] + R[i][1] * cs[1] + R[i][2] * cs[2]);

    float* outR = out + (size_t)b * 9;
    #pragma unroll
    for (int i = 0; i < 3; ++i)
        #pragma unroll
        for (int j = 0; j < 3; ++j)
            outR[i * 3 + j] = (float)R[i][j];
    float* outT = out + (size_t)B * 9 + (size_t)b * 3;
    #pragma unroll
    for (int i = 0; i < 3; ++i) outT[i] = (float)tv[i];
}

extern "C" void kernel_launch(void* const* d_in, const int* in_sizes, int n_in,
                              void* d_out, int out_size, void* d_ws, size_t ws_size,
                              hipStream_t stream) {
    const float* src = (const float*)d_in[0];
    const float* tgt = (const float*)d_in[1];
    const float* wts = (const float*)d_in[2];
    float* out = (float*)d_out;
    float* ws = (float*)d_ws;   // 16 floats per batch = 512 KB
    const int B = out_size / 12;  // 9 (R) + 3 (t) floats per batch; B=8192

    wproc_moments<<<B, BLOCK, 0, stream>>>(src, tgt, wts, ws);
    wproc_solve<<<(B + BLOCK_S - 1) / BLOCK_S, BLOCK_S, 0, stream>>>(ws, out, B);
}